// Round 11
// baseline (356.584 us; speedup 1.0000x reference)
//
#include <hip/hip_runtime.h>

// STN round 11: conv1 on the MATRIX pipe (v_mfma_f32_16x16x32_f16).
// r5-r10 showed K1's VALU-issue time (~224-250us) is conserved under every
// VALU-side restructuring. Conv1 (the largest term) moves to MFMA:
//   C[16ch(8 used) x 16 pos], K = (c,kh)x8kw-pad = 6 ksteps, 198 MFMA/image.
//   A = weights, fragment-prestaged in LDS. B = image window; per-lane 16B at
//   2B granularity -> 3 aligned ds_read_b64 + funnel-shift extract (static).
//   N = (yoff,x) 2x8 so pool = shfl_xor(8) vertical, shfl_xor(1) horizontal.
// One wave per image, 4 images/block. conv2/fc1/fc2/staging/K2 = r10 verbatim.

typedef _Float16 f16x8 __attribute__((ext_vector_type(8)));
typedef float f32x4 __attribute__((ext_vector_type(4)));

__launch_bounds__(256, 4)
__global__ void stn_loc_kernel(
    const float* __restrict__ x,
    const float* __restrict__ w1, const float* __restrict__ b1,
    const float* __restrict__ w2, const float* __restrict__ b2,
    const float* __restrict__ fc1w, const float* __restrict__ fc1b,
    const float* __restrict__ fc2w, const float* __restrict__ fc2b,
    float* __restrict__ theta_ws)
{
    __shared__ uint2 s_img64[4 * 840];                      // 26880 B: 4 x [3][28][40] f16
    __shared__ __align__(16) _Float16 s_afrag[6 * 64 * 8];  // 6144 B: A-frags, frag-ordered
    __shared__ __align__(16) float s_h1[4][8 * 11 * 12];    // 16896 B pooled1 fp32
    __shared__ float s_h2[4][90];
    __shared__ float s_fch[4][32];

    const int t = threadIdx.x;
    const int nb = blockIdx.x;                  // 4096 blocks, 4 images each

    // ---- Stage A: 4 images HWC fp32 -> LDS CHW f16 (+zero col pads)
    for (int im = 0; im < 4; ++im) {
        const float* img = x + ((size_t)(nb * 4 + im)) * 2352;
        _Float16* imh = ((_Float16*)s_img64) + im * 3360;
        for (int p = t; p < 784; p += 256) {
            const int h = p / 28, w = p - 28 * h;
            imh[(0 * 28 + h) * 40 + w] = (_Float16)img[3 * p + 0];
            imh[(1 * 28 + h) * 40 + w] = (_Float16)img[3 * p + 1];
            imh[(2 * 28 + h) * 40 + w] = (_Float16)img[3 * p + 2];
        }
        for (int idx = t; idx < 504; idx += 256) {
            const int cc = idx / 168;
            const int rem = idx - 168 * cc;
            const int hh = rem / 6;
            const int kk = rem - 6 * hh;
            ((uint32_t*)imh)[(((cc * 28 + hh) * 40) + 28 + 2 * kk) >> 1] = 0u;
        }
    }
    // conv1 weights -> A fragments, exactly the MFMA lane order:
    // A[o = lane&15][k = (lane>>4)*8 + j] = w1[o][c][kh][j], pair = ks*4 + (lane>>4)
    for (int d = t; d < 3072; d += 256) {
        const int ks = d >> 9;
        const int ln = (d >> 3) & 63;
        const int j  = d & 7;
        const int o  = ln & 15;
        const int pp = ln >> 4;
        const int pair = ks * 4 + pp;
        float v = 0.0f;
        if (o < 8 && pair < 21 && j < 7) {
            const int c = pair / 7, kh = pair - 7 * c;
            v = w1[((o * 3 + c) * 7 + kh) * 7 + j];
        }
        s_afrag[(ks * 64 + ln) * 8 + j] = (_Float16)v;
    }
    __syncthreads();

    // ---- Stage B: conv1 via MFMA + 2x2 maxpool + relu -> s_h1[wv] (fp32)
    // wave wv owns image wv. lane l: p = l>>4 (k-group), n = l&15 = yoff*8 + x.
    {
        const int l  = t & 63;
        const int wv = t >> 6;
        const int p  = l >> 4;
        const int nn = l & 15;
        const int yoff = nn >> 3;
        const int xx = nn & 7;

        f16x8 af[6];
        #pragma unroll
        for (int ks = 0; ks < 6; ++ks)
            af[ks] = *(const f16x8*)&s_afrag[(ks * 64 + l) * 8];

        int poff[6];
        #pragma unroll
        for (int ks = 0; ks < 6; ++ks) {
            const int pair = ks * 4 + p;
            if (pair < 21) {
                const int c = pair / 7, kh = pair - 7 * c;
                poff[ks] = (c * 28 + kh) * 80;
            } else {
                poff[ks] = 0;   // zero-weight pad pair: read valid memory, A=0
            }
        }
        const int base0 = wv * 6720 + yoff * 80 + xx * 2;

        float bia[4];
        #pragma unroll
        for (int r = 0; r < 4; ++r) bia[r] = b1[(p & 1) * 4 + r];

        for (int yt = 0; yt < 11; ++yt) {
            #pragma unroll
            for (int xt = 0; xt < 3; ++xt) {
                f32x4 acc = {0.0f, 0.0f, 0.0f, 0.0f};
                #pragma unroll
                for (int ks = 0; ks < 6; ++ks) {
                    // B[k=p*8+j][n] = img[c][2yt+yoff+kh][8xt + xx + j]
                    const int s = base0 + poff[ks] + yt * 160 + xt * 16;
                    const int idx = s >> 3;
                    const uint2 d0 = s_img64[idx];
                    const uint2 d1 = s_img64[idx + 1];
                    const uint2 d2 = s_img64[idx + 2];
                    const uint32_t shb = (uint32_t)(s & 2) * 8u;   // 0 or 16
                    const bool qq = (s & 4) != 0;
                    // funnel-shift chain (compiles to v_alignbit / lshr_b64)
                    const uint32_t e0 = (uint32_t)(((((uint64_t)d0.y) << 32) | d0.x) >> shb);
                    const uint32_t e1 = (uint32_t)(((((uint64_t)d1.x) << 32) | d0.y) >> shb);
                    const uint32_t e2 = (uint32_t)(((((uint64_t)d1.y) << 32) | d1.x) >> shb);
                    const uint32_t e3 = (uint32_t)(((((uint64_t)d2.x) << 32) | d1.y) >> shb);
                    const uint32_t e4 = (uint32_t)(((((uint64_t)d2.y) << 32) | d2.x) >> shb);
                    union { uint32_t u[4]; f16x8 h; } bf;
                    bf.u[0] = qq ? e1 : e0;
                    bf.u[1] = qq ? e2 : e1;
                    bf.u[2] = qq ? e3 : e2;
                    bf.u[3] = qq ? e4 : e3;
                    acc = __builtin_amdgcn_mfma_f32_16x16x32_f16(af[ks], bf.h, acc, 0, 0, 0);
                }
                // C[row = p*4 + r][col = n]: pool vert (n^8) then horiz (n^1)
                float pv[4];
                #pragma unroll
                for (int r = 0; r < 4; ++r) {
                    const float a_ = acc[r];
                    const float vb = __shfl_xor(a_, 8);
                    const float m1 = fmaxf(a_, vb);
                    const float hc = __shfl_xor(m1, 1);
                    pv[r] = fmaxf(m1, hc);
                }
                if (p < 2 && (nn & 9) == 0 && !(xt == 2 && xx >= 6)) {
                    const int pc = xt * 4 + (xx >> 1);      // pooled col 0..10
                    #pragma unroll
                    for (int r = 0; r < 4; ++r) {
                        const int o = p * 4 + r;
                        s_h1[wv][(o * 11 + yt) * 12 + pc] = fmaxf(pv[r] + bia[r], 0.0f);
                    }
                }
            }
        }
    }
    __syncthreads();

    // ---- Stage D: conv2 + maxpool + relu, 240 threads = 4 im x 60 (r10 verbatim)
    if (t < 240) {
        const int im = t / 60;
        const int r = t - 60 * im;
        const int o = r / 6, i = r - 6 * (r / 6);
        float acc2[6];
        const float bias = b2[o];
        #pragma unroll
        for (int j = 0; j < 6; ++j) acc2[j] = bias;
        for (int c = 0; c < 8; ++c) {
            #pragma unroll
            for (int kh = 0; kh < 5; ++kh) {
                const float* hrow = &s_h1[im][(c * 11 + i + kh) * 12];
                float im2[12];
                #pragma unroll
                for (int qq = 0; qq < 3; ++qq) {
                    float4 v = ((const float4*)hrow)[qq];
                    im2[4 * qq + 0] = v.x; im2[4 * qq + 1] = v.y;
                    im2[4 * qq + 2] = v.z; im2[4 * qq + 3] = v.w;
                }
                const float* wr = &w2[(o * 8 + c) * 25 + kh * 5];
                float wv5[5];
                #pragma unroll
                for (int qq = 0; qq < 5; ++qq) wv5[qq] = wr[qq];
                #pragma unroll
                for (int kw = 0; kw < 5; ++kw) {
                    #pragma unroll
                    for (int j = 0; j < 6; ++j)
                        acc2[j] += im2[j + kw] * wv5[kw];
                }
            }
        }
        float hp[3];
        #pragma unroll
        for (int qq = 0; qq < 3; ++qq) hp[qq] = fmaxf(acc2[2 * qq], acc2[2 * qq + 1]);
        #pragma unroll
        for (int qq = 0; qq < 3; ++qq) {
            float v = __shfl_xor(hp[qq], 1);   // partner i^1 = t^1 (60*im even)
            hp[qq] = fmaxf(hp[qq], v);
        }
        if ((i & 1) == 0) {
            #pragma unroll
            for (int qq = 0; qq < 3; ++qq)
                s_h2[im][o * 9 + (i >> 1) * 3 + qq] = fmaxf(hp[qq], 0.0f);
        }
    }
    __syncthreads();

    // ---- Stage F: fc1 (90->32) + relu; 256 threads = 4 im x 32 of x 2 lanes
    {
        const int im = t >> 6;
        const int of = (t >> 1) & 31;
        const int l = t & 1;
        float acc = 0.0f;
        const float* wr = &fc1w[of * 90];
        #pragma unroll
        for (int j = 0; j < 45; ++j) {
            const int jj = l + 2 * j;
            acc += s_h2[im][jj] * wr[jj];
        }
        acc += __shfl_xor(acc, 1);
        if (l == 0) s_fch[im][of] = fmaxf(acc + fc1b[of], 0.0f);
    }
    __syncthreads();

    // ---- Stage G: fc2 (32->6); 192 threads = 4 im x 6 of x 8 lanes
    if (t < 192) {
        const int im = t / 48;
        const int r = t - 48 * im;
        const int of = r >> 3, l = r & 7;
        float acc = 0.0f;
        const float* wr = &fc2w[of * 32];
        #pragma unroll
        for (int m = 0; m < 4; ++m) {
            const int j = l + 8 * m;
            acc += s_fch[im][j] * wr[j];
        }
        acc += __shfl_xor(acc, 1);
        acc += __shfl_xor(acc, 2);
        acc += __shfl_xor(acc, 4);
        if (l == 0) theta_ws[((size_t)(nb * 4 + im)) * 6 + of] = acc + fc2b[of];
    }
}

__launch_bounds__(256)
__global__ void stn_sample_kernel(
    const float* __restrict__ x,
    const float* __restrict__ theta_ws,
    float* __restrict__ out)
{
    const int t = threadIdx.x;
    const int n = blockIdx.x;
    const float* tw = theta_ws + (size_t)n * 6;
    const float t00 = tw[0], t01 = tw[1], t02 = tw[2];
    const float t10 = tw[3], t11 = tw[4], t12 = tw[5];
    const float* img = x + (size_t)n * 2352;       // HWC
    float* outp = out + (size_t)n * 2352;

    for (int p = t; p < 784; p += 256) {
        int h = p / 28, w = p - 28 * h;
        float xs = (2.0f * w + 1.0f) * (1.0f / 28.0f) - 1.0f;
        float ys = (2.0f * h + 1.0f) * (1.0f / 28.0f) - 1.0f;
        float gx = t00 * xs + t01 * ys + t02;
        float gy = t10 * xs + t11 * ys + t12;
        float ix = ((gx + 1.0f) * 28.0f - 1.0f) * 0.5f;
        float iy = ((gy + 1.0f) * 28.0f - 1.0f) * 0.5f;
        float x0f = floorf(ix), y0f = floorf(iy);
        float wx1 = ix - x0f, wx0 = 1.0f - wx1;
        float wy1 = iy - y0f, wy0 = 1.0f - wy1;
        int x0 = (int)x0f, y0 = (int)y0f;
        int x1 = x0 + 1, y1 = y0 + 1;
        float fx0 = (x0 >= 0 && x0 < 28) ? 1.0f : 0.0f;
        float fx1 = (x1 >= 0 && x1 < 28) ? 1.0f : 0.0f;
        float fy0 = (y0 >= 0 && y0 < 28) ? 1.0f : 0.0f;
        float fy1 = (y1 >= 0 && y1 < 28) ? 1.0f : 0.0f;
        float w00 = wx0 * wy0 * fx0 * fy0;
        float w10 = wx1 * wy0 * fx1 * fy0;
        float w01 = wx0 * wy1 * fx0 * fy1;
        float w11 = wx1 * wy1 * fx1 * fy1;
        int cx0 = min(max(x0, 0), 27), cx1 = min(max(x1, 0), 27);
        int cy0 = min(max(y0, 0), 27), cy1 = min(max(y1, 0), 27);
        const float* p00 = img + (cy0 * 28 + cx0) * 3;
        const float* p10 = img + (cy0 * 28 + cx1) * 3;
        const float* p01 = img + (cy1 * 28 + cx0) * 3;
        const float* p11 = img + (cy1 * 28 + cx1) * 3;
        float* o3 = outp + 3 * p;
        #pragma unroll
        for (int c = 0; c < 3; ++c) {
            o3[c] = p00[c] * w00 + p10[c] * w10 + p01[c] * w01 + p11[c] * w11;
        }
    }
}

extern "C" void kernel_launch(void* const* d_in, const int* in_sizes, int n_in,
                              void* d_out, int out_size, void* d_ws, size_t ws_size,
                              hipStream_t stream) {
    const float* x     = (const float*)d_in[0];
    const float* w1    = (const float*)d_in[1];
    const float* b1    = (const float*)d_in[2];
    const float* w2    = (const float*)d_in[3];
    const float* b2    = (const float*)d_in[4];
    const float* fc1w  = (const float*)d_in[5];
    const float* fc1b  = (const float*)d_in[6];
    const float* fc2w  = (const float*)d_in[7];
    const float* fc2b  = (const float*)d_in[8];
    float* outp  = (float*)d_out;
    float* theta = (float*)d_ws;   // 16384*6 floats = 393 KB

    const int n_img = 64 * 256;  // b*n
    stn_loc_kernel<<<dim3(n_img / 4), dim3(256), 0, stream>>>(
        x, w1, b1, w2, b2, fc1w, fc1b, fc2w, fc2b, theta);
    stn_sample_kernel<<<dim3(n_img), dim3(256), 0, stream>>>(x, theta, outp);
}

// Round 12
// 285.127 us; speedup vs baseline: 1.2506x; 1.2506x over previous
//
#include <hip/hip_runtime.h>

// STN round 12: r10 base (best, 312us) + two provable instruction cuts:
//  (a) conv1 O-window builds via __builtin_amdgcn_alignbit (1 inst guaranteed)
//  (b) conv2 -> channel-paired fdot2: h1 stored as f16 c-pair dwords
//      [4im][4c2][10][12] (row/col 10 never read by conv2), w2 staged as
//      paired f16 in LDS [o][100]. Conv2 MACs and LDS reads both halve.
// Everything else r10-verbatim.

typedef _Float16 half2_t __attribute__((ext_vector_type(2)));

static __device__ inline half2_t h2(uint32_t u) {
    union { uint32_t u; half2_t h; } cv; cv.u = u; return cv.h;
}
static __device__ inline uint32_t packh2(float a, float b) {
    union { half2_t h; uint32_t u; } cv;
    cv.h = (half2_t){(_Float16)a, (_Float16)b};
    return cv.u;
}

#if __has_builtin(__builtin_amdgcn_fdot2)
#define FDOT2(a, b, c) __builtin_amdgcn_fdot2((a), (b), (c), false)
#else
#define FDOT2(a, b, c) ((float)(a)[0] * (float)(b)[0] + (float)(a)[1] * (float)(b)[1] + (c))
#endif

#if __has_builtin(__builtin_amdgcn_alignbit)
#define ALIGN16(hi, lo) __builtin_amdgcn_alignbit((hi), (lo), 16)
#else
#define ALIGN16(hi, lo) (((lo) >> 16) | ((hi) << 16))
#endif

__launch_bounds__(256, 4)
__global__ void stn_loc_kernel(
    const float* __restrict__ x,
    const float* __restrict__ w1, const float* __restrict__ b1,
    const float* __restrict__ w2, const float* __restrict__ b2,
    const float* __restrict__ fc1w, const float* __restrict__ fc1b,
    const float* __restrict__ fc2w, const float* __restrict__ fc2b,
    float* __restrict__ theta_ws)
{
    __shared__ __align__(16) _Float16 s_imgh[4][3 * 28 * 40];  // 26880 B
    __shared__ __align__(16) uint32_t s_w1p[8 * 21 * 4];       // 2688 B
    __shared__ __align__(16) uint32_t s_h1p[4 * 4 * 10 * 12];  // 7680 B: f16 c-pairs
    __shared__ __align__(16) uint32_t s_w2h[10 * 100];         // 4000 B: f16 c-pairs
    __shared__ float s_h2[4][90];
    __shared__ float s_fch[4][32];

    const int t = threadIdx.x;
    const int nb = blockIdx.x;                  // 4096 blocks, 4 images each

    // ---- Stage A: 4 images HWC fp32 -> LDS CHW f16 (+col pads), weights
    for (int im = 0; im < 4; ++im) {
        const float* img = x + ((size_t)(nb * 4 + im)) * 2352;
        for (int p = t; p < 784; p += 256) {
            const int h = p / 28, w = p - 28 * h;
            s_imgh[im][(0 * 28 + h) * 40 + w] = (_Float16)img[3 * p + 0];
            s_imgh[im][(1 * 28 + h) * 40 + w] = (_Float16)img[3 * p + 1];
            s_imgh[im][(2 * 28 + h) * 40 + w] = (_Float16)img[3 * p + 2];
        }
        for (int idx = t; idx < 504; idx += 256) {
            const int cc = idx / 168;
            const int rem = idx - 168 * cc;
            const int hh = rem / 6;
            const int kk = rem - 6 * hh;
            ((uint32_t*)s_imgh[im])[(((cc * 28 + hh) * 40) + 28 + 2 * kk) >> 1] = 0u;
        }
    }
    // conv1 weights -> half2 kw-pairs
    for (int idx = t; idx < 672; idx += 256) {
        const int o = idx / 84;  const int rem = idx - 84 * o;
        const int c = rem / 28;  const int r2 = rem - 28 * c;
        const int kh = r2 >> 2;  const int p = r2 & 3;
        const int k0 = 2 * p;
        const float* wbase = &w1[((o * 3 + c) * 7 + kh) * 7];
        const float wa = wbase[k0];
        const float wb = (k0 + 1 < 7) ? wbase[k0 + 1] : 0.0f;
        s_w1p[idx] = packh2(wa, wb);
    }
    // conv2 weights -> f16 channel-pairs: s_w2h[o*100 + (c2*5+kh)*5 + kw]
    for (int k = t; k < 1000; k += 256) {
        const int o = k / 100;
        const int rem = k - 100 * o;       // (c2*5+kh)*5 + kw
        const int c2kh = rem / 5;
        const int kw = rem - 5 * c2kh;
        const int c2 = c2kh / 5;
        const int kh = c2kh - 5 * c2;
        s_w2h[k] = packh2(w2[((o * 8 + 2 * c2) * 5 + kh) * 5 + kw],
                          w2[((o * 8 + 2 * c2 + 1) * 5 + kh) * 5 + kw]);
    }
    __syncthreads();

    // ---- Stage B: conv1 + maxpool + relu, 704 units = 4 im x (22 rows x 8 ch)
    for (int u = t; u < 704; u += 256) {
        const int im = u / 176;
        const int r  = u - 176 * im;
        const int i = r >> 3, o = r & 7;
        float acc[22];
        #pragma unroll
        for (int j = 0; j < 22; ++j) acc[j] = 0.0f;

        for (int c = 0; c < 3; ++c) {
            #pragma unroll
            for (int kh = 0; kh < 7; ++kh) {
                const uint32_t* rowu =
                    (const uint32_t*)&s_imgh[im][(c * 28 + i + kh) * 40];
                uint32_t E[16];
                {
                    const uint4 a = ((const uint4*)rowu)[0];
                    const uint4 b = ((const uint4*)rowu)[1];
                    const uint4 cq = ((const uint4*)rowu)[2];
                    const uint4 d = ((const uint4*)rowu)[3];
                    E[0] = a.x;  E[1] = a.y;  E[2] = a.z;  E[3] = a.w;
                    E[4] = b.x;  E[5] = b.y;  E[6] = b.z;  E[7] = b.w;
                    E[8] = cq.x; E[9] = cq.y; E[10] = cq.z; E[11] = cq.w;
                    E[12] = d.x; E[13] = d.y; E[14] = d.z; E[15] = d.w;
                }
                uint32_t O[14];
                #pragma unroll
                for (int k = 0; k < 14; ++k)
                    O[k] = ALIGN16(E[k + 1], E[k]);

                const uint4 wq = *(const uint4*)&s_w1p[(o * 21 + c * 7 + kh) * 4];
                const half2_t wp0 = h2(wq.x), wp1 = h2(wq.y);
                const half2_t wp2 = h2(wq.z), wp3 = h2(wq.w);

                #pragma unroll
                for (int j = 0; j < 22; j += 2) {
                    const int b0 = j >> 1;
                    acc[j]     = FDOT2(h2(E[b0]),     wp0, acc[j]);
                    acc[j]     = FDOT2(h2(E[b0 + 1]), wp1, acc[j]);
                    acc[j]     = FDOT2(h2(E[b0 + 2]), wp2, acc[j]);
                    acc[j]     = FDOT2(h2(E[b0 + 3]), wp3, acc[j]);
                    acc[j + 1] = FDOT2(h2(O[b0]),     wp0, acc[j + 1]);
                    acc[j + 1] = FDOT2(h2(O[b0 + 1]), wp1, acc[j + 1]);
                    acc[j + 1] = FDOT2(h2(O[b0 + 2]), wp2, acc[j + 1]);
                    acc[j + 1] = FDOT2(h2(O[b0 + 3]), wp3, acc[j + 1]);
                }
            }
        }
        const float bias = b1[o];
        float hm[11];
        #pragma unroll
        for (int j = 0; j < 11; ++j) hm[j] = fmaxf(acc[2 * j], acc[2 * j + 1]);
        #pragma unroll
        for (int j = 0; j < 11; ++j) {
            float v = __shfl_xor(hm[j], 8);   // partner: same im, row i^1
            hm[j] = fmaxf(hm[j], v);
        }
        // write f16 c-pair halves; conv2 never reads pooled row 10 / col 10
        if ((i & 1) == 0 && i < 20) {
            const int c2 = o >> 1, u2 = i >> 1;
            _Float16* dst = ((_Float16*)s_h1p)
                          + (((im * 4 + c2) * 10 + u2) * 12) * 2 + (o & 1);
            #pragma unroll
            for (int m = 0; m < 10; ++m)
                dst[2 * m] = (_Float16)fmaxf(hm[m] + bias, 0.0f);
        }
    }
    __syncthreads();

    // ---- Stage D: conv2 via c-paired fdot2 + maxpool + relu, 240 thr = 4im x 60
    if (t < 240) {
        const int im = t / 60;
        const int r = t - 60 * im;
        const int o = r / 6, i = r - 6 * (r / 6);
        float acc2[6];
        #pragma unroll
        for (int j = 0; j < 6; ++j) acc2[j] = 0.0f;
        #pragma unroll
        for (int c2 = 0; c2 < 4; ++c2) {
            #pragma unroll
            for (int kh = 0; kh < 5; ++kh) {
                const uint32_t* row = &s_h1p[((im * 4 + c2) * 10 + (i + kh)) * 12];
                uint32_t E[12];
                {
                    const uint4 a = ((const uint4*)row)[0];
                    const uint4 b = ((const uint4*)row)[1];
                    const uint4 cq = ((const uint4*)row)[2];
                    E[0] = a.x;  E[1] = a.y;  E[2] = a.z;  E[3] = a.w;
                    E[4] = b.x;  E[5] = b.y;  E[6] = b.z;  E[7] = b.w;
                    E[8] = cq.x; E[9] = cq.y; E[10] = cq.z; E[11] = cq.w;
                }
                const uint32_t* wb = &s_w2h[o * 100 + (c2 * 5 + kh) * 5];
                const half2_t w0 = h2(wb[0]), w1_ = h2(wb[1]), w2_ = h2(wb[2]),
                              w3_ = h2(wb[3]), w4_ = h2(wb[4]);
                #pragma unroll
                for (int j = 0; j < 6; ++j) {
                    float a_ = acc2[j];
                    a_ = FDOT2(h2(E[j]),     w0,  a_);
                    a_ = FDOT2(h2(E[j + 1]), w1_, a_);
                    a_ = FDOT2(h2(E[j + 2]), w2_, a_);
                    a_ = FDOT2(h2(E[j + 3]), w3_, a_);
                    a_ = FDOT2(h2(E[j + 4]), w4_, a_);
                    acc2[j] = a_;
                }
            }
        }
        const float bias = b2[o];
        float hp[3];
        #pragma unroll
        for (int q = 0; q < 3; ++q) hp[q] = fmaxf(acc2[2 * q], acc2[2 * q + 1]);
        #pragma unroll
        for (int q = 0; q < 3; ++q) {
            float v = __shfl_xor(hp[q], 1);   // partner i^1 = t^1 (60*im even)
            hp[q] = fmaxf(hp[q], v);
        }
        if ((i & 1) == 0) {
            #pragma unroll
            for (int q = 0; q < 3; ++q)
                s_h2[im][o * 9 + (i >> 1) * 3 + q] = fmaxf(hp[q] + bias, 0.0f);
        }
    }
    __syncthreads();

    // ---- Stage F: fc1 (90->32) + relu; 256 threads = 4 im x 32 of x 2 lanes
    {
        const int im = t >> 6;
        const int of = (t >> 1) & 31;
        const int l = t & 1;
        float acc = 0.0f;
        const float* wr = &fc1w[of * 90];
        #pragma unroll
        for (int j = 0; j < 45; ++j) {
            const int jj = l + 2 * j;
            acc += s_h2[im][jj] * wr[jj];
        }
        acc += __shfl_xor(acc, 1);
        if (l == 0) s_fch[im][of] = fmaxf(acc + fc1b[of], 0.0f);
    }
    __syncthreads();

    // ---- Stage G: fc2 (32->6); 192 threads = 4 im x 6 of x 8 lanes
    if (t < 192) {
        const int im = t / 48;
        const int r = t - 48 * im;
        const int of = r >> 3, l = r & 7;
        float acc = 0.0f;
        const float* wr = &fc2w[of * 32];
        #pragma unroll
        for (int m = 0; m < 4; ++m) {
            const int j = l + 8 * m;
            acc += s_fch[im][j] * wr[j];
        }
        acc += __shfl_xor(acc, 1);
        acc += __shfl_xor(acc, 2);
        acc += __shfl_xor(acc, 4);
        if (l == 0) theta_ws[((size_t)(nb * 4 + im)) * 6 + of] = acc + fc2b[of];
    }
}

__launch_bounds__(256)
__global__ void stn_sample_kernel(
    const float* __restrict__ x,
    const float* __restrict__ theta_ws,
    float* __restrict__ out)
{
    const int t = threadIdx.x;
    const int n = blockIdx.x;
    const float* tw = theta_ws + (size_t)n * 6;
    const float t00 = tw[0], t01 = tw[1], t02 = tw[2];
    const float t10 = tw[3], t11 = tw[4], t12 = tw[5];
    const float* img = x + (size_t)n * 2352;       // HWC
    float* outp = out + (size_t)n * 2352;

    for (int p = t; p < 784; p += 256) {
        int h = p / 28, w = p - 28 * h;
        float xs = (2.0f * w + 1.0f) * (1.0f / 28.0f) - 1.0f;
        float ys = (2.0f * h + 1.0f) * (1.0f / 28.0f) - 1.0f;
        float gx = t00 * xs + t01 * ys + t02;
        float gy = t10 * xs + t11 * ys + t12;
        float ix = ((gx + 1.0f) * 28.0f - 1.0f) * 0.5f;
        float iy = ((gy + 1.0f) * 28.0f - 1.0f) * 0.5f;
        float x0f = floorf(ix), y0f = floorf(iy);
        float wx1 = ix - x0f, wx0 = 1.0f - wx1;
        float wy1 = iy - y0f, wy0 = 1.0f - wy1;
        int x0 = (int)x0f, y0 = (int)y0f;
        int x1 = x0 + 1, y1 = y0 + 1;
        float fx0 = (x0 >= 0 && x0 < 28) ? 1.0f : 0.0f;
        float fx1 = (x1 >= 0 && x1 < 28) ? 1.0f : 0.0f;
        float fy0 = (y0 >= 0 && y0 < 28) ? 1.0f : 0.0f;
        float fy1 = (y1 >= 0 && y1 < 28) ? 1.0f : 0.0f;
        float w00 = wx0 * wy0 * fx0 * fy0;
        float w10 = wx1 * wy0 * fx1 * fy0;
        float w01 = wx0 * wy1 * fx0 * fy1;
        float w11 = wx1 * wy1 * fx1 * fy1;
        int cx0 = min(max(x0, 0), 27), cx1 = min(max(x1, 0), 27);
        int cy0 = min(max(y0, 0), 27), cy1 = min(max(y1, 0), 27);
        const float* p00 = img + (cy0 * 28 + cx0) * 3;
        const float* p10 = img + (cy0 * 28 + cx1) * 3;
        const float* p01 = img + (cy1 * 28 + cx0) * 3;
        const float* p11 = img + (cy1 * 28 + cx1) * 3;
        float* o3 = outp + 3 * p;
        #pragma unroll
        for (int c = 0; c < 3; ++c) {
            o3[c] = p00[c] * w00 + p10[c] * w10 + p01[c] * w01 + p11[c] * w11;
        }
    }
}

extern "C" void kernel_launch(void* const* d_in, const int* in_sizes, int n_in,
                              void* d_out, int out_size, void* d_ws, size_t ws_size,
                              hipStream_t stream) {
    const float* x     = (const float*)d_in[0];
    const float* w1    = (const float*)d_in[1];
    const float* b1    = (const float*)d_in[2];
    const float* w2    = (const float*)d_in[3];
    const float* b2    = (const float*)d_in[4];
    const float* fc1w  = (const float*)d_in[5];
    const float* fc1b  = (const float*)d_in[6];
    const float* fc2w  = (const float*)d_in[7];
    const float* fc2b  = (const float*)d_in[8];
    float* outp  = (float*)d_out;
    float* theta = (float*)d_ws;   // 16384*6 floats = 393 KB

    const int n_img = 64 * 256;  // b*n
    stn_loc_kernel<<<dim3(n_img / 4), dim3(256), 0, stream>>>(
        x, w1, b1, w2, b2, fc1w, fc1b, fc2w, fc2b, theta);
    stn_sample_kernel<<<dim3(n_img), dim3(256), 0, stream>>>(x, theta, outp);
}

// Round 13
// 268.976 us; speedup vs baseline: 1.3257x; 1.0600x over previous
//
#include <hip/hip_runtime.h>

// STN round 13: r12 base + cross the 4-blocks/CU LDS threshold.
//  - K0 pre-pack (once): w2 f16 c-pairs + fc1w f16 pairs -> d_ws (global,
//    L1/L2-hot table; r10 precedent for in-loop global weight reads).
//  - s_h2 -> f16-pair dwords [4][48]; fc1 = 23 fdot2/lane (r9-proven).
//  - LDS 43.5KB -> 37.6KB => 4 blocks/CU (16 waves/CU, was 12).
// Everything else r12-verbatim.

typedef _Float16 half2_t __attribute__((ext_vector_type(2)));

static __device__ inline half2_t h2(uint32_t u) {
    union { uint32_t u; half2_t h; } cv; cv.u = u; return cv.h;
}
static __device__ inline uint32_t packh2(float a, float b) {
    union { half2_t h; uint32_t u; } cv;
    cv.h = (half2_t){(_Float16)a, (_Float16)b};
    return cv.u;
}

#if __has_builtin(__builtin_amdgcn_fdot2)
#define FDOT2(a, b, c) __builtin_amdgcn_fdot2((a), (b), (c), false)
#else
#define FDOT2(a, b, c) ((float)(a)[0] * (float)(b)[0] + (float)(a)[1] * (float)(b)[1] + (c))
#endif

#if __has_builtin(__builtin_amdgcn_alignbit)
#define ALIGN16(hi, lo) __builtin_amdgcn_alignbit((hi), (lo), 16)
#else
#define ALIGN16(hi, lo) (((lo) >> 16) | ((hi) << 16))
#endif

// ---- K0: one-block weight pre-pack into workspace
__launch_bounds__(256)
__global__ void stn_pack_kernel(
    const float* __restrict__ w2, const float* __restrict__ fc1w,
    uint32_t* __restrict__ w2p, uint32_t* __restrict__ fc1p)
{
    const int t = threadIdx.x;
    // w2 -> f16 channel-pairs: w2p[o*100 + (c2*5+kh)*5 + kw]
    for (int k = t; k < 1000; k += 256) {
        const int o = k / 100;
        const int rem = k - 100 * o;
        const int c2kh = rem / 5;
        const int kw = rem - 5 * c2kh;
        const int c2 = c2kh / 5;
        const int kh = c2kh - 5 * c2;
        w2p[k] = packh2(w2[((o * 8 + 2 * c2) * 5 + kh) * 5 + kw],
                        w2[((o * 8 + 2 * c2 + 1) * 5 + kh) * 5 + kw]);
    }
    // fc1w -> f16 j-pairs: fc1p[of*46 + p], p<45 real, p=45 zero pad
    for (int k = t; k < 1472; k += 256) {
        const int of = k / 46;
        const int p = k - 46 * of;
        uint32_t v = 0;
        if (p < 45) v = packh2(fc1w[of * 90 + 2 * p], fc1w[of * 90 + 2 * p + 1]);
        fc1p[k] = v;
    }
}

__launch_bounds__(256, 4)
__global__ void stn_loc_kernel(
    const float* __restrict__ x,
    const float* __restrict__ w1, const float* __restrict__ b1,
    const uint32_t* __restrict__ w2p, const float* __restrict__ b2,
    const uint32_t* __restrict__ fc1p, const float* __restrict__ fc1b,
    const float* __restrict__ fc2w, const float* __restrict__ fc2b,
    float* __restrict__ theta_ws)
{
    __shared__ __align__(16) _Float16 s_imgh[4][3 * 28 * 40];  // 26880 B
    __shared__ __align__(16) uint32_t s_w1p[8 * 21 * 4];       // 2688 B
    __shared__ __align__(16) uint32_t s_h1p[4 * 4 * 10 * 12];  // 7680 B f16 c-pairs
    __shared__ __align__(16) uint32_t s_h2p[4][48];            // 768 B f16 pairs
    __shared__ float s_fch[4][32];                             // 512 B

    const int t = threadIdx.x;
    const int nb = blockIdx.x;                  // 4096 blocks, 4 images each

    // ---- Stage A: 4 images HWC fp32 -> LDS CHW f16 (+col pads); w1 pairs; pads
    for (int im = 0; im < 4; ++im) {
        const float* img = x + ((size_t)(nb * 4 + im)) * 2352;
        for (int p = t; p < 784; p += 256) {
            const int h = p / 28, w = p - 28 * h;
            s_imgh[im][(0 * 28 + h) * 40 + w] = (_Float16)img[3 * p + 0];
            s_imgh[im][(1 * 28 + h) * 40 + w] = (_Float16)img[3 * p + 1];
            s_imgh[im][(2 * 28 + h) * 40 + w] = (_Float16)img[3 * p + 2];
        }
        for (int idx = t; idx < 504; idx += 256) {
            const int cc = idx / 168;
            const int rem = idx - 168 * cc;
            const int hh = rem / 6;
            const int kk = rem - 6 * hh;
            ((uint32_t*)s_imgh[im])[(((cc * 28 + hh) * 40) + 28 + 2 * kk) >> 1] = 0u;
        }
    }
    for (int idx = t; idx < 672; idx += 256) {
        const int o = idx / 84;  const int rem = idx - 84 * o;
        const int c = rem / 28;  const int r2 = rem - 28 * c;
        const int kh = r2 >> 2;  const int p = r2 & 3;
        const int k0 = 2 * p;
        const float* wbase = &w1[((o * 3 + c) * 7 + kh) * 7];
        const float wa = wbase[k0];
        const float wb = (k0 + 1 < 7) ? wbase[k0 + 1] : 0.0f;
        s_w1p[idx] = packh2(wa, wb);
    }
    if (t < 12) s_h2p[t / 3][45 + t % 3] = 0u;   // zero pads for fc1
    __syncthreads();

    // ---- Stage B: conv1 + maxpool + relu, 704 units = 4 im x (22 rows x 8 ch)
    for (int u = t; u < 704; u += 256) {
        const int im = u / 176;
        const int r  = u - 176 * im;
        const int i = r >> 3, o = r & 7;
        float acc[22];
        #pragma unroll
        for (int j = 0; j < 22; ++j) acc[j] = 0.0f;

        for (int c = 0; c < 3; ++c) {
            #pragma unroll
            for (int kh = 0; kh < 7; ++kh) {
                const uint32_t* rowu =
                    (const uint32_t*)&s_imgh[im][(c * 28 + i + kh) * 40];
                uint32_t E[16];
                {
                    const uint4 a = ((const uint4*)rowu)[0];
                    const uint4 b = ((const uint4*)rowu)[1];
                    const uint4 cq = ((const uint4*)rowu)[2];
                    const uint4 d = ((const uint4*)rowu)[3];
                    E[0] = a.x;  E[1] = a.y;  E[2] = a.z;  E[3] = a.w;
                    E[4] = b.x;  E[5] = b.y;  E[6] = b.z;  E[7] = b.w;
                    E[8] = cq.x; E[9] = cq.y; E[10] = cq.z; E[11] = cq.w;
                    E[12] = d.x; E[13] = d.y; E[14] = d.z; E[15] = d.w;
                }
                uint32_t O[14];
                #pragma unroll
                for (int k = 0; k < 14; ++k)
                    O[k] = ALIGN16(E[k + 1], E[k]);

                const uint4 wq = *(const uint4*)&s_w1p[(o * 21 + c * 7 + kh) * 4];
                const half2_t wp0 = h2(wq.x), wp1 = h2(wq.y);
                const half2_t wp2 = h2(wq.z), wp3 = h2(wq.w);

                #pragma unroll
                for (int j = 0; j < 22; j += 2) {
                    const int b0 = j >> 1;
                    acc[j]     = FDOT2(h2(E[b0]),     wp0, acc[j]);
                    acc[j]     = FDOT2(h2(E[b0 + 1]), wp1, acc[j]);
                    acc[j]     = FDOT2(h2(E[b0 + 2]), wp2, acc[j]);
                    acc[j]     = FDOT2(h2(E[b0 + 3]), wp3, acc[j]);
                    acc[j + 1] = FDOT2(h2(O[b0]),     wp0, acc[j + 1]);
                    acc[j + 1] = FDOT2(h2(O[b0 + 1]), wp1, acc[j + 1]);
                    acc[j + 1] = FDOT2(h2(O[b0 + 2]), wp2, acc[j + 1]);
                    acc[j + 1] = FDOT2(h2(O[b0 + 3]), wp3, acc[j + 1]);
                }
            }
        }
        const float bias = b1[o];
        float hm[11];
        #pragma unroll
        for (int j = 0; j < 11; ++j) hm[j] = fmaxf(acc[2 * j], acc[2 * j + 1]);
        #pragma unroll
        for (int j = 0; j < 11; ++j) {
            float v = __shfl_xor(hm[j], 8);   // partner: same im, row i^1
            hm[j] = fmaxf(hm[j], v);
        }
        if ((i & 1) == 0 && i < 20) {
            const int c2 = o >> 1, u2 = i >> 1;
            _Float16* dst = ((_Float16*)s_h1p)
                          + (((im * 4 + c2) * 10 + u2) * 12) * 2 + (o & 1);
            #pragma unroll
            for (int m = 0; m < 10; ++m)
                dst[2 * m] = (_Float16)fmaxf(hm[m] + bias, 0.0f);
        }
    }
    __syncthreads();

    // ---- Stage D: conv2 via c-paired fdot2, weights from global packed table
    if (t < 240) {
        const int im = t / 60;
        const int r = t - 60 * im;
        const int o = r / 6, i = r - 6 * (r / 6);
        float acc2[6];
        #pragma unroll
        for (int j = 0; j < 6; ++j) acc2[j] = 0.0f;
        for (int c2 = 0; c2 < 4; ++c2) {
            #pragma unroll
            for (int kh = 0; kh < 5; ++kh) {
                const uint32_t* row = &s_h1p[((im * 4 + c2) * 10 + (i + kh)) * 12];
                uint32_t E[12];
                {
                    const uint4 a = ((const uint4*)row)[0];
                    const uint4 b = ((const uint4*)row)[1];
                    const uint4 cq = ((const uint4*)row)[2];
                    E[0] = a.x;  E[1] = a.y;  E[2] = a.z;  E[3] = a.w;
                    E[4] = b.x;  E[5] = b.y;  E[6] = b.z;  E[7] = b.w;
                    E[8] = cq.x; E[9] = cq.y; E[10] = cq.z; E[11] = cq.w;
                }
                const uint32_t* wb = &w2p[o * 100 + (c2 * 5 + kh) * 5];
                const half2_t w0 = h2(wb[0]), w1_ = h2(wb[1]), w2_ = h2(wb[2]),
                              w3_ = h2(wb[3]), w4_ = h2(wb[4]);
                #pragma unroll
                for (int j = 0; j < 6; ++j) {
                    float a_ = acc2[j];
                    a_ = FDOT2(h2(E[j]),     w0,  a_);
                    a_ = FDOT2(h2(E[j + 1]), w1_, a_);
                    a_ = FDOT2(h2(E[j + 2]), w2_, a_);
                    a_ = FDOT2(h2(E[j + 3]), w3_, a_);
                    a_ = FDOT2(h2(E[j + 4]), w4_, a_);
                    acc2[j] = a_;
                }
            }
        }
        const float bias = b2[o];
        float hp[3];
        #pragma unroll
        for (int q = 0; q < 3; ++q) hp[q] = fmaxf(acc2[2 * q], acc2[2 * q + 1]);
        #pragma unroll
        for (int q = 0; q < 3; ++q) {
            float v = __shfl_xor(hp[q], 1);   // partner i^1 = t^1 (60*im even)
            hp[q] = fmaxf(hp[q], v);
        }
        if ((i & 1) == 0) {
            #pragma unroll
            for (int q = 0; q < 3; ++q)
                ((_Float16*)&s_h2p[im][0])[o * 9 + (i >> 1) * 3 + q] =
                    (_Float16)fmaxf(hp[q] + bias, 0.0f);
        }
    }
    __syncthreads();

    // ---- Stage F: fc1 (90->32) + relu; paired fdot2, weights from global table
    {
        const int im = t >> 6;
        const int of = (t >> 1) & 31;
        const int l = t & 1;
        float acc = 0.0f;
        const uint32_t* wr = &fc1p[of * 46];
        #pragma unroll
        for (int m = 0; m < 23; ++m) {
            const int q = l + 2 * m;      // <= 45; pair 45 is zero
            acc = FDOT2(h2(s_h2p[im][q]), h2(wr[q]), acc);
        }
        acc += __shfl_xor(acc, 1);
        if (l == 0) s_fch[im][of] = fmaxf(acc + fc1b[of], 0.0f);
    }
    __syncthreads();

    // ---- Stage G: fc2 (32->6); 192 threads = 4 im x 6 of x 8 lanes
    if (t < 192) {
        const int im = t / 48;
        const int r = t - 48 * im;
        const int of = r >> 3, l = r & 7;
        float acc = 0.0f;
        const float* wr = &fc2w[of * 32];
        #pragma unroll
        for (int m = 0; m < 4; ++m) {
            const int j = l + 8 * m;
            acc += s_fch[im][j] * wr[j];
        }
        acc += __shfl_xor(acc, 1);
        acc += __shfl_xor(acc, 2);
        acc += __shfl_xor(acc, 4);
        if (l == 0) theta_ws[((size_t)(nb * 4 + im)) * 6 + of] = acc + fc2b[of];
    }
}

__launch_bounds__(256)
__global__ void stn_sample_kernel(
    const float* __restrict__ x,
    const float* __restrict__ theta_ws,
    float* __restrict__ out)
{
    const int t = threadIdx.x;
    const int n = blockIdx.x;
    const float* tw = theta_ws + (size_t)n * 6;
    const float t00 = tw[0], t01 = tw[1], t02 = tw[2];
    const float t10 = tw[3], t11 = tw[4], t12 = tw[5];
    const float* img = x + (size_t)n * 2352;       // HWC
    float* outp = out + (size_t)n * 2352;

    for (int p = t; p < 784; p += 256) {
        int h = p / 28, w = p - 28 * h;
        float xs = (2.0f * w + 1.0f) * (1.0f / 28.0f) - 1.0f;
        float ys = (2.0f * h + 1.0f) * (1.0f / 28.0f) - 1.0f;
        float gx = t00 * xs + t01 * ys + t02;
        float gy = t10 * xs + t11 * ys + t12;
        float ix = ((gx + 1.0f) * 28.0f - 1.0f) * 0.5f;
        float iy = ((gy + 1.0f) * 28.0f - 1.0f) * 0.5f;
        float x0f = floorf(ix), y0f = floorf(iy);
        float wx1 = ix - x0f, wx0 = 1.0f - wx1;
        float wy1 = iy - y0f, wy0 = 1.0f - wy1;
        int x0 = (int)x0f, y0 = (int)y0f;
        int x1 = x0 + 1, y1 = y0 + 1;
        float fx0 = (x0 >= 0 && x0 < 28) ? 1.0f : 0.0f;
        float fx1 = (x1 >= 0 && x1 < 28) ? 1.0f : 0.0f;
        float fy0 = (y0 >= 0 && y0 < 28) ? 1.0f : 0.0f;
        float fy1 = (y1 >= 0 && y1 < 28) ? 1.0f : 0.0f;
        float w00 = wx0 * wy0 * fx0 * fy0;
        float w10 = wx1 * wy0 * fx1 * fy0;
        float w01 = wx0 * wy1 * fx0 * fy1;
        float w11 = wx1 * wy1 * fx1 * fy1;
        int cx0 = min(max(x0, 0), 27), cx1 = min(max(x1, 0), 27);
        int cy0 = min(max(y0, 0), 27), cy1 = min(max(y1, 0), 27);
        const float* p00 = img + (cy0 * 28 + cx0) * 3;
        const float* p10 = img + (cy0 * 28 + cx1) * 3;
        const float* p01 = img + (cy1 * 28 + cx0) * 3;
        const float* p11 = img + (cy1 * 28 + cx1) * 3;
        float* o3 = outp + 3 * p;
        #pragma unroll
        for (int c = 0; c < 3; ++c) {
            o3[c] = p00[c] * w00 + p10[c] * w10 + p01[c] * w01 + p11[c] * w11;
        }
    }
}

extern "C" void kernel_launch(void* const* d_in, const int* in_sizes, int n_in,
                              void* d_out, int out_size, void* d_ws, size_t ws_size,
                              hipStream_t stream) {
    const float* x     = (const float*)d_in[0];
    const float* w1    = (const float*)d_in[1];
    const float* b1    = (const float*)d_in[2];
    const float* w2    = (const float*)d_in[3];
    const float* b2    = (const float*)d_in[4];
    const float* fc1w  = (const float*)d_in[5];
    const float* fc1b  = (const float*)d_in[6];
    const float* fc2w  = (const float*)d_in[7];
    const float* fc2b  = (const float*)d_in[8];
    float* outp  = (float*)d_out;

    // workspace layout: [0,98304) theta floats; then packed weight tables
    float*    theta = (float*)d_ws;                       // 16384*6
    uint32_t* w2p   = (uint32_t*)d_ws + 98304;            // 1000 dwords (pad 1024)
    uint32_t* fc1p  = (uint32_t*)d_ws + 98304 + 1024;     // 1472 dwords

    const int n_img = 64 * 256;  // b*n
    stn_pack_kernel<<<dim3(1), dim3(256), 0, stream>>>(w2, fc1w, w2p, fc1p);
    stn_loc_kernel<<<dim3(n_img / 4), dim3(256), 0, stream>>>(
        x, w1, b1, w2p, b2, fc1p, fc1b, fc2w, fc2b, theta);
    stn_sample_kernel<<<dim3(n_img), dim3(256), 0, stream>>>(x, theta, outp);
}

// Round 14
// 263.251 us; speedup vs baseline: 1.3545x; 1.0217x over previous
//
#include <hip/hip_runtime.h>

// STN round 14: r13 base + sampling merged INTO the loc kernel.
// K2 was write-bound (~25us, 154MB) and stream-serialized behind all K1
// blocks. Merged, each block samples from its still-LDS-resident f16 image
// right after theta, so output stores overlap other blocks' conv compute.
// Also: pad-zeroing folded into the pixel staging loop; theta ws removed.
// Conv1/conv2/fc bodies r13-verbatim (proven).

typedef _Float16 half2_t __attribute__((ext_vector_type(2)));

static __device__ inline half2_t h2(uint32_t u) {
    union { uint32_t u; half2_t h; } cv; cv.u = u; return cv.h;
}
static __device__ inline uint32_t packh2(float a, float b) {
    union { half2_t h; uint32_t u; } cv;
    cv.h = (half2_t){(_Float16)a, (_Float16)b};
    return cv.u;
}

#if __has_builtin(__builtin_amdgcn_fdot2)
#define FDOT2(a, b, c) __builtin_amdgcn_fdot2((a), (b), (c), false)
#else
#define FDOT2(a, b, c) ((float)(a)[0] * (float)(b)[0] + (float)(a)[1] * (float)(b)[1] + (c))
#endif

#if __has_builtin(__builtin_amdgcn_alignbit)
#define ALIGN16(hi, lo) __builtin_amdgcn_alignbit((hi), (lo), 16)
#else
#define ALIGN16(hi, lo) (((lo) >> 16) | ((hi) << 16))
#endif

// ---- K0: one-block weight pre-pack into workspace
__launch_bounds__(256)
__global__ void stn_pack_kernel(
    const float* __restrict__ w2, const float* __restrict__ fc1w,
    uint32_t* __restrict__ w2p, uint32_t* __restrict__ fc1p)
{
    const int t = threadIdx.x;
    for (int k = t; k < 1000; k += 256) {
        const int o = k / 100;
        const int rem = k - 100 * o;
        const int c2kh = rem / 5;
        const int kw = rem - 5 * c2kh;
        const int c2 = c2kh / 5;
        const int kh = c2kh - 5 * c2;
        w2p[k] = packh2(w2[((o * 8 + 2 * c2) * 5 + kh) * 5 + kw],
                        w2[((o * 8 + 2 * c2 + 1) * 5 + kh) * 5 + kw]);
    }
    for (int k = t; k < 1472; k += 256) {
        const int of = k / 46;
        const int p = k - 46 * of;
        uint32_t v = 0;
        if (p < 45) v = packh2(fc1w[of * 90 + 2 * p], fc1w[of * 90 + 2 * p + 1]);
        fc1p[k] = v;
    }
}

__launch_bounds__(256, 4)
__global__ void stn_fused_kernel(
    const float* __restrict__ x,
    const float* __restrict__ w1, const float* __restrict__ b1,
    const uint32_t* __restrict__ w2p, const float* __restrict__ b2,
    const uint32_t* __restrict__ fc1p, const float* __restrict__ fc1b,
    const float* __restrict__ fc2w, const float* __restrict__ fc2b,
    float* __restrict__ out)
{
    __shared__ __align__(16) _Float16 s_imgh[4][3 * 28 * 40];  // 26880 B
    __shared__ __align__(16) uint32_t s_w1p[8 * 21 * 4];       // 2688 B
    __shared__ __align__(16) uint32_t s_h1p[4 * 4 * 10 * 12];  // 7680 B f16 c-pairs
    __shared__ __align__(16) uint32_t s_h2p[4][48];            // 768 B f16 pairs
    __shared__ float s_fch[4][32];                             // 512 B
    __shared__ float s_th[4][8];                               // 128 B theta

    const int t = threadIdx.x;
    const int nb = blockIdx.x;                  // 4096 blocks, 4 images each

    // ---- Stage A: 4 images HWC fp32 -> LDS CHW f16; pad-zeroing folded in
    for (int im = 0; im < 4; ++im) {
        const float* img = x + ((size_t)(nb * 4 + im)) * 2352;
        for (int p = t; p < 784; p += 256) {
            const int h = p / 28, w = p - 28 * h;
            s_imgh[im][(0 * 28 + h) * 40 + w] = (_Float16)img[3 * p + 0];
            s_imgh[im][(1 * 28 + h) * 40 + w] = (_Float16)img[3 * p + 1];
            s_imgh[im][(2 * 28 + h) * 40 + w] = (_Float16)img[3 * p + 2];
            if (w < 12) {
                s_imgh[im][(0 * 28 + h) * 40 + 28 + w] = (_Float16)0.0f;
                s_imgh[im][(1 * 28 + h) * 40 + 28 + w] = (_Float16)0.0f;
                s_imgh[im][(2 * 28 + h) * 40 + 28 + w] = (_Float16)0.0f;
            }
        }
    }
    for (int idx = t; idx < 672; idx += 256) {
        const int o = idx / 84;  const int rem = idx - 84 * o;
        const int c = rem / 28;  const int r2 = rem - 28 * c;
        const int kh = r2 >> 2;  const int p = r2 & 3;
        const int k0 = 2 * p;
        const float* wbase = &w1[((o * 3 + c) * 7 + kh) * 7];
        const float wa = wbase[k0];
        const float wb = (k0 + 1 < 7) ? wbase[k0 + 1] : 0.0f;
        s_w1p[idx] = packh2(wa, wb);
    }
    if (t < 12) s_h2p[t / 3][45 + t % 3] = 0u;   // zero pads for fc1
    __syncthreads();

    // ---- Stage B: conv1 + maxpool + relu, 704 units = 4 im x (22 rows x 8 ch)
    for (int u = t; u < 704; u += 256) {
        const int im = u / 176;
        const int r  = u - 176 * im;
        const int i = r >> 3, o = r & 7;
        float acc[22];
        #pragma unroll
        for (int j = 0; j < 22; ++j) acc[j] = 0.0f;

        for (int c = 0; c < 3; ++c) {
            #pragma unroll
            for (int kh = 0; kh < 7; ++kh) {
                const uint32_t* rowu =
                    (const uint32_t*)&s_imgh[im][(c * 28 + i + kh) * 40];
                uint32_t E[16];
                {
                    const uint4 a = ((const uint4*)rowu)[0];
                    const uint4 b = ((const uint4*)rowu)[1];
                    const uint4 cq = ((const uint4*)rowu)[2];
                    const uint4 d = ((const uint4*)rowu)[3];
                    E[0] = a.x;  E[1] = a.y;  E[2] = a.z;  E[3] = a.w;
                    E[4] = b.x;  E[5] = b.y;  E[6] = b.z;  E[7] = b.w;
                    E[8] = cq.x; E[9] = cq.y; E[10] = cq.z; E[11] = cq.w;
                    E[12] = d.x; E[13] = d.y; E[14] = d.z; E[15] = d.w;
                }
                uint32_t O[14];
                #pragma unroll
                for (int k = 0; k < 14; ++k)
                    O[k] = ALIGN16(E[k + 1], E[k]);

                const uint4 wq = *(const uint4*)&s_w1p[(o * 21 + c * 7 + kh) * 4];
                const half2_t wp0 = h2(wq.x), wp1 = h2(wq.y);
                const half2_t wp2 = h2(wq.z), wp3 = h2(wq.w);

                #pragma unroll
                for (int j = 0; j < 22; j += 2) {
                    const int b0 = j >> 1;
                    acc[j]     = FDOT2(h2(E[b0]),     wp0, acc[j]);
                    acc[j]     = FDOT2(h2(E[b0 + 1]), wp1, acc[j]);
                    acc[j]     = FDOT2(h2(E[b0 + 2]), wp2, acc[j]);
                    acc[j]     = FDOT2(h2(E[b0 + 3]), wp3, acc[j]);
                    acc[j + 1] = FDOT2(h2(O[b0]),     wp0, acc[j + 1]);
                    acc[j + 1] = FDOT2(h2(O[b0 + 1]), wp1, acc[j + 1]);
                    acc[j + 1] = FDOT2(h2(O[b0 + 2]), wp2, acc[j + 1]);
                    acc[j + 1] = FDOT2(h2(O[b0 + 3]), wp3, acc[j + 1]);
                }
            }
        }
        const float bias = b1[o];
        float hm[11];
        #pragma unroll
        for (int j = 0; j < 11; ++j) hm[j] = fmaxf(acc[2 * j], acc[2 * j + 1]);
        #pragma unroll
        for (int j = 0; j < 11; ++j) {
            float v = __shfl_xor(hm[j], 8);   // partner: same im, row i^1
            hm[j] = fmaxf(hm[j], v);
        }
        if ((i & 1) == 0 && i < 20) {
            const int c2 = o >> 1, u2 = i >> 1;
            _Float16* dst = ((_Float16*)s_h1p)
                          + (((im * 4 + c2) * 10 + u2) * 12) * 2 + (o & 1);
            #pragma unroll
            for (int m = 0; m < 10; ++m)
                dst[2 * m] = (_Float16)fmaxf(hm[m] + bias, 0.0f);
        }
    }
    __syncthreads();

    // ---- Stage D: conv2 via c-paired fdot2, weights from global packed table
    if (t < 240) {
        const int im = t / 60;
        const int r = t - 60 * im;
        const int o = r / 6, i = r - 6 * (r / 6);
        float acc2[6];
        #pragma unroll
        for (int j = 0; j < 6; ++j) acc2[j] = 0.0f;
        for (int c2 = 0; c2 < 4; ++c2) {
            #pragma unroll
            for (int kh = 0; kh < 5; ++kh) {
                const uint32_t* row = &s_h1p[((im * 4 + c2) * 10 + (i + kh)) * 12];
                uint32_t E[12];
                {
                    const uint4 a = ((const uint4*)row)[0];
                    const uint4 b = ((const uint4*)row)[1];
                    const uint4 cq = ((const uint4*)row)[2];
                    E[0] = a.x;  E[1] = a.y;  E[2] = a.z;  E[3] = a.w;
                    E[4] = b.x;  E[5] = b.y;  E[6] = b.z;  E[7] = b.w;
                    E[8] = cq.x; E[9] = cq.y; E[10] = cq.z; E[11] = cq.w;
                }
                const uint32_t* wb = &w2p[o * 100 + (c2 * 5 + kh) * 5];
                const half2_t w0 = h2(wb[0]), w1_ = h2(wb[1]), w2_ = h2(wb[2]),
                              w3_ = h2(wb[3]), w4_ = h2(wb[4]);
                #pragma unroll
                for (int j = 0; j < 6; ++j) {
                    float a_ = acc2[j];
                    a_ = FDOT2(h2(E[j]),     w0,  a_);
                    a_ = FDOT2(h2(E[j + 1]), w1_, a_);
                    a_ = FDOT2(h2(E[j + 2]), w2_, a_);
                    a_ = FDOT2(h2(E[j + 3]), w3_, a_);
                    a_ = FDOT2(h2(E[j + 4]), w4_, a_);
                    acc2[j] = a_;
                }
            }
        }
        const float bias = b2[o];
        float hp[3];
        #pragma unroll
        for (int q = 0; q < 3; ++q) hp[q] = fmaxf(acc2[2 * q], acc2[2 * q + 1]);
        #pragma unroll
        for (int q = 0; q < 3; ++q) {
            float v = __shfl_xor(hp[q], 1);   // partner i^1 = t^1 (60*im even)
            hp[q] = fmaxf(hp[q], v);
        }
        if ((i & 1) == 0) {
            #pragma unroll
            for (int q = 0; q < 3; ++q)
                ((_Float16*)&s_h2p[im][0])[o * 9 + (i >> 1) * 3 + q] =
                    (_Float16)fmaxf(hp[q] + bias, 0.0f);
        }
    }
    __syncthreads();

    // ---- Stage F: fc1 (90->32) + relu; paired fdot2, weights from global table
    {
        const int im = t >> 6;
        const int of = (t >> 1) & 31;
        const int l = t & 1;
        float acc = 0.0f;
        const uint32_t* wr = &fc1p[of * 46];
        #pragma unroll
        for (int m = 0; m < 23; ++m) {
            const int q = l + 2 * m;      // <= 45; pair 45 is zero
            acc = FDOT2(h2(s_h2p[im][q]), h2(wr[q]), acc);
        }
        acc += __shfl_xor(acc, 1);
        if (l == 0) s_fch[im][of] = fmaxf(acc + fc1b[of], 0.0f);
    }
    __syncthreads();

    // ---- Stage G: fc2 (32->6); 192 threads = 4 im x 6 of x 8 lanes -> s_th
    if (t < 192) {
        const int im = t / 48;
        const int r = t - 48 * im;
        const int of = r >> 3, l = r & 7;
        float acc = 0.0f;
        const float* wr = &fc2w[of * 32];
        #pragma unroll
        for (int m = 0; m < 4; ++m) {
            const int j = l + 8 * m;
            acc += s_fch[im][j] * wr[j];
        }
        acc += __shfl_xor(acc, 1);
        acc += __shfl_xor(acc, 2);
        acc += __shfl_xor(acc, 4);
        if (l == 0) s_th[im][of] = acc + fc2b[of];
    }
    __syncthreads();

    // ---- Stage H: affine grid + bilinear sample from LDS f16 image -> out
    // 3136 px (4 images); stores overlap other blocks' conv phases.
    for (int u = t; u < 3136; u += 256) {
        const int im = u / 784;
        const int p = u - 784 * im;
        const int h = p / 28, w = p - 28 * h;
        const float t00 = s_th[im][0], t01 = s_th[im][1], t02 = s_th[im][2];
        const float t10 = s_th[im][3], t11 = s_th[im][4], t12 = s_th[im][5];
        const float xs = (2.0f * w + 1.0f) * (1.0f / 28.0f) - 1.0f;
        const float ys = (2.0f * h + 1.0f) * (1.0f / 28.0f) - 1.0f;
        const float gx = t00 * xs + t01 * ys + t02;
        const float gy = t10 * xs + t11 * ys + t12;
        const float ix = ((gx + 1.0f) * 28.0f - 1.0f) * 0.5f;
        const float iy = ((gy + 1.0f) * 28.0f - 1.0f) * 0.5f;
        const float x0f = floorf(ix), y0f = floorf(iy);
        const float wx1 = ix - x0f, wx0 = 1.0f - wx1;
        const float wy1 = iy - y0f, wy0 = 1.0f - wy1;
        const int x0 = (int)x0f, y0 = (int)y0f;
        const int x1 = x0 + 1, y1 = y0 + 1;
        const float fx0 = (x0 >= 0 && x0 < 28) ? 1.0f : 0.0f;
        const float fx1 = (x1 >= 0 && x1 < 28) ? 1.0f : 0.0f;
        const float fy0 = (y0 >= 0 && y0 < 28) ? 1.0f : 0.0f;
        const float fy1 = (y1 >= 0 && y1 < 28) ? 1.0f : 0.0f;
        const float w00 = wx0 * wy0 * fx0 * fy0;
        const float w10 = wx1 * wy0 * fx1 * fy0;
        const float w01 = wx0 * wy1 * fx0 * fy1;
        const float w11 = wx1 * wy1 * fx1 * fy1;
        const int cx0 = min(max(x0, 0), 27), cx1 = min(max(x1, 0), 27);
        const int cy0 = min(max(y0, 0), 27), cy1 = min(max(y1, 0), 27);
        const _Float16* imh = s_imgh[im];
        float* o3 = out + ((size_t)(nb * 4 + im)) * 2352 + 3 * p;
        #pragma unroll
        for (int c = 0; c < 3; ++c) {
            const _Float16* ic = imh + c * 1120;   // 28*40
            const float v = (float)ic[cy0 * 40 + cx0] * w00
                          + (float)ic[cy0 * 40 + cx1] * w10
                          + (float)ic[cy1 * 40 + cx0] * w01
                          + (float)ic[cy1 * 40 + cx1] * w11;
            o3[c] = v;
        }
    }
}

extern "C" void kernel_launch(void* const* d_in, const int* in_sizes, int n_in,
                              void* d_out, int out_size, void* d_ws, size_t ws_size,
                              hipStream_t stream) {
    const float* x     = (const float*)d_in[0];
    const float* w1    = (const float*)d_in[1];
    const float* b1    = (const float*)d_in[2];
    const float* w2    = (const float*)d_in[3];
    const float* b2    = (const float*)d_in[4];
    const float* fc1w  = (const float*)d_in[5];
    const float* fc1b  = (const float*)d_in[6];
    const float* fc2w  = (const float*)d_in[7];
    const float* fc2b  = (const float*)d_in[8];
    float* outp = (float*)d_out;

    // workspace: packed weight tables
    uint32_t* w2p  = (uint32_t*)d_ws;          // 1000 dwords (pad 1024)
    uint32_t* fc1p = (uint32_t*)d_ws + 1024;   // 1472 dwords

    const int n_img = 64 * 256;  // b*n
    stn_pack_kernel<<<dim3(1), dim3(256), 0, stream>>>(w2, fc1w, w2p, fc1p);
    stn_fused_kernel<<<dim3(n_img / 4), dim3(256), 0, stream>>>(
        x, w1, b1, w2p, b2, fc1p, fc1b, fc2w, fc2b, outp);
}

// Round 15
// 263.023 us; speedup vs baseline: 1.3557x; 1.0009x over previous
//
#include <hip/hip_runtime.h>

// STN round 15: conv1 inner product via v_pk_fma_f16 (VOP3P packed f16).
// Rate hypothesis: fdot2/pk_fma_f32 are half-rate on gfx950 (r5==r8 parity,
// r6/r7 nulls), but pk_fma_f16 is historically full-rate = 2x MAC throughput.
// f16 partials kept short (49 terms per c-group), promoted to fp32 accs 3x
// per unit. Weight splats built in-register via v_perm_b32 from the existing
// pair table (no LDS growth). Everything else r14-verbatim.

typedef _Float16 half2_t __attribute__((ext_vector_type(2)));

static __device__ inline half2_t h2(uint32_t u) {
    union { uint32_t u; half2_t h; } cv; cv.u = u; return cv.h;
}
static __device__ inline uint32_t packh2(float a, float b) {
    union { half2_t h; uint32_t u; } cv;
    cv.h = (half2_t){(_Float16)a, (_Float16)b};
    return cv.u;
}

#if __has_builtin(__builtin_amdgcn_perm)
static __device__ inline half2_t splat_lo(uint32_t u) {
    return h2(__builtin_amdgcn_perm(u, u, 0x01000100u));
}
static __device__ inline half2_t splat_hi(uint32_t u) {
    return h2(__builtin_amdgcn_perm(u, u, 0x03020302u));
}
#else
static __device__ inline half2_t splat_lo(uint32_t u) {
    const uint32_t lo = u & 0xFFFFu; return h2(lo | (lo << 16));
}
static __device__ inline half2_t splat_hi(uint32_t u) {
    const uint32_t hi_ = u >> 16; return h2(hi_ | (hi_ << 16));
}
#endif

#if __has_builtin(__builtin_amdgcn_fdot2)
#define FDOT2(a, b, c) __builtin_amdgcn_fdot2((a), (b), (c), false)
#else
#define FDOT2(a, b, c) ((float)(a)[0] * (float)(b)[0] + (float)(a)[1] * (float)(b)[1] + (c))
#endif

#if __has_builtin(__builtin_amdgcn_alignbit)
#define ALIGN16(hi, lo) __builtin_amdgcn_alignbit((hi), (lo), 16)
#else
#define ALIGN16(hi, lo) (((lo) >> 16) | ((hi) << 16))
#endif

// ---- K0: one-block weight pre-pack into workspace
__launch_bounds__(256)
__global__ void stn_pack_kernel(
    const float* __restrict__ w2, const float* __restrict__ fc1w,
    uint32_t* __restrict__ w2p, uint32_t* __restrict__ fc1p)
{
    const int t = threadIdx.x;
    for (int k = t; k < 1000; k += 256) {
        const int o = k / 100;
        const int rem = k - 100 * o;
        const int c2kh = rem / 5;
        const int kw = rem - 5 * c2kh;
        const int c2 = c2kh / 5;
        const int kh = c2kh - 5 * c2;
        w2p[k] = packh2(w2[((o * 8 + 2 * c2) * 5 + kh) * 5 + kw],
                        w2[((o * 8 + 2 * c2 + 1) * 5 + kh) * 5 + kw]);
    }
    for (int k = t; k < 1472; k += 256) {
        const int of = k / 46;
        const int p = k - 46 * of;
        uint32_t v = 0;
        if (p < 45) v = packh2(fc1w[of * 90 + 2 * p], fc1w[of * 90 + 2 * p + 1]);
        fc1p[k] = v;
    }
}

__launch_bounds__(256, 4)
__global__ void stn_fused_kernel(
    const float* __restrict__ x,
    const float* __restrict__ w1, const float* __restrict__ b1,
    const uint32_t* __restrict__ w2p, const float* __restrict__ b2,
    const uint32_t* __restrict__ fc1p, const float* __restrict__ fc1b,
    const float* __restrict__ fc2w, const float* __restrict__ fc2b,
    float* __restrict__ out)
{
    __shared__ __align__(16) _Float16 s_imgh[4][3 * 28 * 40];  // 26880 B
    __shared__ __align__(16) uint32_t s_w1p[8 * 21 * 4];       // 2688 B
    __shared__ __align__(16) uint32_t s_h1p[4 * 4 * 10 * 12];  // 7680 B f16 c-pairs
    __shared__ __align__(16) uint32_t s_h2p[4][48];            // 768 B f16 pairs
    __shared__ float s_fch[4][32];                             // 512 B
    __shared__ float s_th[4][8];                               // 128 B theta

    const int t = threadIdx.x;
    const int nb = blockIdx.x;                  // 4096 blocks, 4 images each

    // ---- Stage A: 4 images HWC fp32 -> LDS CHW f16; pad-zeroing folded in
    for (int im = 0; im < 4; ++im) {
        const float* img = x + ((size_t)(nb * 4 + im)) * 2352;
        for (int p = t; p < 784; p += 256) {
            const int h = p / 28, w = p - 28 * h;
            s_imgh[im][(0 * 28 + h) * 40 + w] = (_Float16)img[3 * p + 0];
            s_imgh[im][(1 * 28 + h) * 40 + w] = (_Float16)img[3 * p + 1];
            s_imgh[im][(2 * 28 + h) * 40 + w] = (_Float16)img[3 * p + 2];
            if (w < 12) {
                s_imgh[im][(0 * 28 + h) * 40 + 28 + w] = (_Float16)0.0f;
                s_imgh[im][(1 * 28 + h) * 40 + 28 + w] = (_Float16)0.0f;
                s_imgh[im][(2 * 28 + h) * 40 + 28 + w] = (_Float16)0.0f;
            }
        }
    }
    for (int idx = t; idx < 672; idx += 256) {
        const int o = idx / 84;  const int rem = idx - 84 * o;
        const int c = rem / 28;  const int r2 = rem - 28 * c;
        const int kh = r2 >> 2;  const int p = r2 & 3;
        const int k0 = 2 * p;
        const float* wbase = &w1[((o * 3 + c) * 7 + kh) * 7];
        const float wa = wbase[k0];
        const float wb = (k0 + 1 < 7) ? wbase[k0 + 1] : 0.0f;
        s_w1p[idx] = packh2(wa, wb);
    }
    if (t < 12) s_h2p[t / 3][45 + t % 3] = 0u;   // zero pads for fc1
    __syncthreads();

    // ---- Stage B: conv1 via pk_fma_f16 pairs + maxpool + relu
    // 704 units = 4 im x (22 rows x 8 ch). p[m] = {out[2m], out[2m+1]} f16
    // partial per c-group (49 terms), promoted to fp32 acc after each c.
    for (int u = t; u < 704; u += 256) {
        const int im = u / 176;
        const int r  = u - 176 * im;
        const int i = r >> 3, o = r & 7;
        float acc[22];
        #pragma unroll
        for (int j = 0; j < 22; ++j) acc[j] = 0.0f;

        for (int c = 0; c < 3; ++c) {
            half2_t p[11];
            #pragma unroll
            for (int m = 0; m < 11; ++m) p[m] = (half2_t){(_Float16)0.0f, (_Float16)0.0f};

            #pragma unroll
            for (int kh = 0; kh < 7; ++kh) {
                const uint32_t* rowu =
                    (const uint32_t*)&s_imgh[im][(c * 28 + i + kh) * 40];
                uint32_t E[16];
                {
                    const uint4 a = ((const uint4*)rowu)[0];
                    const uint4 b = ((const uint4*)rowu)[1];
                    const uint4 cq = ((const uint4*)rowu)[2];
                    const uint4 d = ((const uint4*)rowu)[3];
                    E[0] = a.x;  E[1] = a.y;  E[2] = a.z;  E[3] = a.w;
                    E[4] = b.x;  E[5] = b.y;  E[6] = b.z;  E[7] = b.w;
                    E[8] = cq.x; E[9] = cq.y; E[10] = cq.z; E[11] = cq.w;
                    E[12] = d.x; E[13] = d.y; E[14] = d.z; E[15] = d.w;
                }
                uint32_t O[13];
                #pragma unroll
                for (int k = 0; k < 13; ++k)
                    O[k] = ALIGN16(E[k + 1], E[k]);

                const uint4 wq = *(const uint4*)&s_w1p[(o * 21 + c * 7 + kh) * 4];
                const half2_t s0 = splat_lo(wq.x), s1 = splat_hi(wq.x);
                const half2_t s2 = splat_lo(wq.y), s3 = splat_hi(wq.y);
                const half2_t s4 = splat_lo(wq.z), s5 = splat_hi(wq.z);
                const half2_t s6 = splat_lo(wq.w);

                #pragma unroll
                for (int m = 0; m < 11; ++m) {
                    half2_t pm = p[m];
                    pm = __builtin_elementwise_fma(h2(E[m]),     s0, pm);
                    pm = __builtin_elementwise_fma(h2(O[m]),     s1, pm);
                    pm = __builtin_elementwise_fma(h2(E[m + 1]), s2, pm);
                    pm = __builtin_elementwise_fma(h2(O[m + 1]), s3, pm);
                    pm = __builtin_elementwise_fma(h2(E[m + 2]), s4, pm);
                    pm = __builtin_elementwise_fma(h2(O[m + 2]), s5, pm);
                    pm = __builtin_elementwise_fma(h2(E[m + 3]), s6, pm);
                    p[m] = pm;
                }
            }
            // promote c-group partials into fp32 accumulators
            #pragma unroll
            for (int m = 0; m < 11; ++m) {
                acc[2 * m]     += (float)p[m][0];
                acc[2 * m + 1] += (float)p[m][1];
            }
        }
        const float bias = b1[o];
        float hm[11];
        #pragma unroll
        for (int j = 0; j < 11; ++j) hm[j] = fmaxf(acc[2 * j], acc[2 * j + 1]);
        #pragma unroll
        for (int j = 0; j < 11; ++j) {
            float v = __shfl_xor(hm[j], 8);   // partner: same im, row i^1
            hm[j] = fmaxf(hm[j], v);
        }
        if ((i & 1) == 0 && i < 20) {
            const int c2 = o >> 1, u2 = i >> 1;
            _Float16* dst = ((_Float16*)s_h1p)
                          + (((im * 4 + c2) * 10 + u2) * 12) * 2 + (o & 1);
            #pragma unroll
            for (int m = 0; m < 10; ++m)
                dst[2 * m] = (_Float16)fmaxf(hm[m] + bias, 0.0f);
        }
    }
    __syncthreads();

    // ---- Stage D: conv2 via c-paired fdot2, weights from global packed table
    if (t < 240) {
        const int im = t / 60;
        const int r = t - 60 * im;
        const int o = r / 6, i = r - 6 * (r / 6);
        float acc2[6];
        #pragma unroll
        for (int j = 0; j < 6; ++j) acc2[j] = 0.0f;
        for (int c2 = 0; c2 < 4; ++c2) {
            #pragma unroll
            for (int kh = 0; kh < 5; ++kh) {
                const uint32_t* row = &s_h1p[((im * 4 + c2) * 10 + (i + kh)) * 12];
                uint32_t E[12];
                {
                    const uint4 a = ((const uint4*)row)[0];
                    const uint4 b = ((const uint4*)row)[1];
                    const uint4 cq = ((const uint4*)row)[2];
                    E[0] = a.x;  E[1] = a.y;  E[2] = a.z;  E[3] = a.w;
                    E[4] = b.x;  E[5] = b.y;  E[6] = b.z;  E[7] = b.w;
                    E[8] = cq.x; E[9] = cq.y; E[10] = cq.z; E[11] = cq.w;
                }
                const uint32_t* wb = &w2p[o * 100 + (c2 * 5 + kh) * 5];
                const half2_t w0 = h2(wb[0]), w1_ = h2(wb[1]), w2_ = h2(wb[2]),
                              w3_ = h2(wb[3]), w4_ = h2(wb[4]);
                #pragma unroll
                for (int j = 0; j < 6; ++j) {
                    float a_ = acc2[j];
                    a_ = FDOT2(h2(E[j]),     w0,  a_);
                    a_ = FDOT2(h2(E[j + 1]), w1_, a_);
                    a_ = FDOT2(h2(E[j + 2]), w2_, a_);
                    a_ = FDOT2(h2(E[j + 3]), w3_, a_);
                    a_ = FDOT2(h2(E[j + 4]), w4_, a_);
                    acc2[j] = a_;
                }
            }
        }
        const float bias = b2[o];
        float hp[3];
        #pragma unroll
        for (int q = 0; q < 3; ++q) hp[q] = fmaxf(acc2[2 * q], acc2[2 * q + 1]);
        #pragma unroll
        for (int q = 0; q < 3; ++q) {
            float v = __shfl_xor(hp[q], 1);   // partner i^1 = t^1 (60*im even)
            hp[q] = fmaxf(hp[q], v);
        }
        if ((i & 1) == 0) {
            #pragma unroll
            for (int q = 0; q < 3; ++q)
                ((_Float16*)&s_h2p[im][0])[o * 9 + (i >> 1) * 3 + q] =
                    (_Float16)fmaxf(hp[q] + bias, 0.0f);
        }
    }
    __syncthreads();

    // ---- Stage F: fc1 (90->32) + relu; paired fdot2, weights from global table
    {
        const int im = t >> 6;
        const int of = (t >> 1) & 31;
        const int l = t & 1;
        float acc = 0.0f;
        const uint32_t* wr = &fc1p[of * 46];
        #pragma unroll
        for (int m = 0; m < 23; ++m) {
            const int q = l + 2 * m;      // <= 45; pair 45 is zero
            acc = FDOT2(h2(s_h2p[im][q]), h2(wr[q]), acc);
        }
        acc += __shfl_xor(acc, 1);
        if (l == 0) s_fch[im][of] = fmaxf(acc + fc1b[of], 0.0f);
    }
    __syncthreads();

    // ---- Stage G: fc2 (32->6); 192 threads = 4 im x 6 of x 8 lanes -> s_th
    if (t < 192) {
        const int im = t / 48;
        const int r = t - 48 * im;
        const int of = r >> 3, l = r & 7;
        float acc = 0.0f;
        const float* wr = &fc2w[of * 32];
        #pragma unroll
        for (int m = 0; m < 4; ++m) {
            const int j = l + 8 * m;
            acc += s_fch[im][j] * wr[j];
        }
        acc += __shfl_xor(acc, 1);
        acc += __shfl_xor(acc, 2);
        acc += __shfl_xor(acc, 4);
        if (l == 0) s_th[im][of] = acc + fc2b[of];
    }
    __syncthreads();

    // ---- Stage H: affine grid + bilinear sample from LDS f16 image -> out
    for (int u = t; u < 3136; u += 256) {
        const int im = u / 784;
        const int p = u - 784 * im;
        const int h = p / 28, w = p - 28 * h;
        const float t00 = s_th[im][0], t01 = s_th[im][1], t02 = s_th[im][2];
        const float t10 = s_th[im][3], t11 = s_th[im][4], t12 = s_th[im][5];
        const float xs = (2.0f * w + 1.0f) * (1.0f / 28.0f) - 1.0f;
        const float ys = (2.0f * h + 1.0f) * (1.0f / 28.0f) - 1.0f;
        const float gx = t00 * xs + t01 * ys + t02;
        const float gy = t10 * xs + t11 * ys + t12;
        const float ix = ((gx + 1.0f) * 28.0f - 1.0f) * 0.5f;
        const float iy = ((gy + 1.0f) * 28.0f - 1.0f) * 0.5f;
        const float x0f = floorf(ix), y0f = floorf(iy);
        const float wx1 = ix - x0f, wx0 = 1.0f - wx1;
        const float wy1 = iy - y0f, wy0 = 1.0f - wy1;
        const int x0 = (int)x0f, y0 = (int)y0f;
        const int x1 = x0 + 1, y1 = y0 + 1;
        const float fx0 = (x0 >= 0 && x0 < 28) ? 1.0f : 0.0f;
        const float fx1 = (x1 >= 0 && x1 < 28) ? 1.0f : 0.0f;
        const float fy0 = (y0 >= 0 && y0 < 28) ? 1.0f : 0.0f;
        const float fy1 = (y1 >= 0 && y1 < 28) ? 1.0f : 0.0f;
        const float w00 = wx0 * wy0 * fx0 * fy0;
        const float w10 = wx1 * wy0 * fx1 * fy0;
        const float w01 = wx0 * wy1 * fx0 * fy1;
        const float w11 = wx1 * wy1 * fx1 * fy1;
        const int cx0 = min(max(x0, 0), 27), cx1 = min(max(x1, 0), 27);
        const int cy0 = min(max(y0, 0), 27), cy1 = min(max(y1, 0), 27);
        const _Float16* imh = s_imgh[im];
        float* o3 = out + ((size_t)(nb * 4 + im)) * 2352 + 3 * p;
        #pragma unroll
        for (int c = 0; c < 3; ++c) {
            const _Float16* ic = imh + c * 1120;   // 28*40
            const float v = (float)ic[cy0 * 40 + cx0] * w00
                          + (float)ic[cy0 * 40 + cx1] * w10
                          + (float)ic[cy1 * 40 + cx0] * w01
                          + (float)ic[cy1 * 40 + cx1] * w11;
            o3[c] = v;
        }
    }
}

extern "C" void kernel_launch(void* const* d_in, const int* in_sizes, int n_in,
                              void* d_out, int out_size, void* d_ws, size_t ws_size,
                              hipStream_t stream) {
    const float* x     = (const float*)d_in[0];
    const float* w1    = (const float*)d_in[1];
    const float* b1    = (const float*)d_in[2];
    const float* w2    = (const float*)d_in[3];
    const float* b2    = (const float*)d_in[4];
    const float* fc1w  = (const float*)d_in[5];
    const float* fc1b  = (const float*)d_in[6];
    const float* fc2w  = (const float*)d_in[7];
    const float* fc2b  = (const float*)d_in[8];
    float* outp = (float*)d_out;

    // workspace: packed weight tables
    uint32_t* w2p  = (uint32_t*)d_ws;          // 1000 dwords (pad 1024)
    uint32_t* fc1p = (uint32_t*)d_ws + 1024;   // 1472 dwords

    const int n_img = 64 * 256;  // b*n
    stn_pack_kernel<<<dim3(1), dim3(256), 0, stream>>>(w2, fc1w, w2p, fc1p);
    stn_fused_kernel<<<dim3(n_img / 4), dim3(256), 0, stream>>>(
        x, w1, b1, w2p, b2, fc1p, fc1b, fc2w, fc2b, outp);
}